// Round 5
// baseline (54.380 us; speedup 1.0000x reference)
//
#include <hip/hip_runtime.h>
#include <hip/hip_bf16.h>

// int4-dequant GEMM, M=32 (last token), K=4096, N=32000 (of 32064 padded).
// qweight [K][16032] int32, ONE BYTE per word (upper 24 bits zero):
//   lo nibble = even col, hi nibble = odd col. w[k][n] = (q - z)*s, g = k/128.
//
// Structure (round 4) + this round: coalesced prep reads, nontemporal qweight.
//  - prep packs A (x last token, f32->f16) into d_ws fragments; shared
//    k-bijection kappa(h,j)=8h+j for A and B so HW k-order cancels.
//  - aws A-fragments double-buffered (prefetched 1 k-step ahead)
//  - scales/qzeros raw words prefetched 1 group (4 t) ahead
//  - dequant: tcomb=(w1<<16)|w0, mask-only nibble extract:
//    even cols: (tcomb & 0x000F000F)|0x64006400, vz=1024+z,   vs=s
//    odd  cols: (tcomb & 0x00F000F0)|0x64006400, vz=1024+16z, vs=s/16
//  - qweight loads nontemporal (stream-once; don't evict aws/scales from L2)
// Lane c owns phys cols 4c+s; one dwordx2/row covers all 4 sub-tiles.

typedef _Float16 f16x8 __attribute__((ext_vector_type(8)));
typedef _Float16 f16x2 __attribute__((ext_vector_type(2)));
typedef float f32x4 __attribute__((ext_vector_type(4)));
typedef int i32x2 __attribute__((ext_vector_type(2)));

#define K_DIM 4096
#define NP 16032       // packed words per qweight/qzeros row
#define NSC 32064      // scales row pitch
#define NOUT 32000
#define S_LEN 64
#define QROWB ((size_t)NP * 4)          // bytes per qweight row
#define QSTEP (32u * (uint32_t)NP * 4u) // byte advance per k-step (32 rows)

// ---- pre-kernel: pack x[:,63,:] (f32) into A fragments (f16) ----
// aws[((ks*2 + mblk)*64 + h*16 + (m&15))*8 + j] = A[m][32ks + 8h + j]
// Thread (m, q): reads 32 B contiguous (k = 8q..8q+7) -> fully coalesced;
// writes one 16 B fragment (scattered, fire-and-forget).
__global__ void prep_a_kernel(const float* __restrict__ x,
                              _Float16* __restrict__ aws) {
    int tid = blockIdx.x * 256 + threadIdx.x;   // 0..16383
    int m = tid >> 9;           // 0..31
    int q = tid & 511;          // 8-wide k group
    const float* xp = x + ((size_t)m * S_LEN + (S_LEN - 1)) * K_DIM + q * 8;
    f32x4 u0 = *(const f32x4*)xp;
    f32x4 u1 = *(const f32x4*)(xp + 4);
    int ks = q >> 2;
    int h = q & 3;
    int mblk = m >> 4;
    f16x8 d;
#pragma unroll
    for (int j = 0; j < 4; ++j) {
        d[j] = (_Float16)u0[j];
        d[4 + j] = (_Float16)u1[j];
    }
    *(f16x8*)(aws + ((size_t)((ks * 2 + mblk) * 64 + h * 16 + (m & 15))) * 8) = d;
}

// ---- main kernel ----
__global__ __launch_bounds__(512, 4)
void q4gemm_kernel(const int* __restrict__ qw,
                   const float* __restrict__ scales,
                   const int* __restrict__ qzeros,
                   const float* __restrict__ bias,
                   const _Float16* __restrict__ aws,
                   float* __restrict__ out) {
    __shared__ float red[8 * 2048];   // 64 KB: per-wave partial C tiles

    const int tid = threadIdx.x;
    const int w = tid >> 6;          // wave 0..7 (K-chunk: k in [512w, 512w+512))
    const int l = tid & 63;
    const int h = l >> 4;            // k lane-group 0..3 (rows 8h+j)
    const int c = l & 15;            // lane's column group: phys cols 4c+s
    const int n0 = blockIdx.x * 64;
    const int np0 = n0 >> 1;

    const char* qwb = (const char*)qw;
    uint32_t qoff = (uint32_t)((w * 512 + 8 * h) * (size_t)NP + np0 + 2 * c) * 4u;

    f32x4 acc0[4] = {};   // mblk 0, sub s = 2*bs+o
    f32x4 acc1[4] = {};   // mblk 1
    f16x2 vz[4], vs[4];   // expanded per-group constants
    f32x4 gsc;            // raw next-group scales
    i32x2 gzw;            // raw next-group zeros
    i32x2 qa[8], qb[8];
    f16x8 afa0, afa1, afb0, afb1;

#define QLD(buf)                                                              \
    do {                                                                      \
        _Pragma("unroll") for (int j = 0; j < 8; ++j)                         \
            buf[j] = __builtin_nontemporal_load(                              \
                (const i32x2*)(qwb + qoff + (size_t)j * QROWB));              \
        qoff += QSTEP;                                                        \
    } while (0)

#define GRP_LOAD(g)                                                           \
    do {                                                                      \
        int gg = (g) > 31 ? 31 : (g);                                         \
        gsc = *(const f32x4*)(scales + (size_t)gg * NSC + n0 + 4 * c);        \
        gzw = *(const i32x2*)(qzeros + (size_t)gg * NP + np0 + 2 * c);        \
    } while (0)

#define GRP_EXPAND()                                                          \
    do {                                                                      \
        _Pragma("unroll") for (int s = 0; s < 4; ++s) {                       \
            const int bs = s >> 1, o = s & 1;                                 \
            int zn = (gzw[bs] >> (4 * o)) & 15;                               \
            int z16 = 0x6400 | (o ? (zn << 4) : zn);                          \
            int zp = z16 | (z16 << 16);                                       \
            vz[s] = __builtin_bit_cast(f16x2, zp);                            \
            float sf = gsc[s] * (o ? 0.0625f : 1.0f);                         \
            _Float16 hf = (_Float16)sf;                                       \
            f16x2 sp = {hf, hf};                                              \
            vs[s] = sp;                                                       \
        }                                                                     \
    } while (0)

#define ALD(A0, A1, tloc)                                                     \
    do {                                                                      \
        int ksg_ = w * 16 + (tloc);                                           \
        A0 = *(const f16x8*)(aws + ((size_t)(ksg_ * 2 + 0) * 64 + l) * 8);    \
        A1 = *(const f16x8*)(aws + ((size_t)(ksg_ * 2 + 1) * 64 + l) * 8);    \
    } while (0)

#define COMPUTE(buf, A0, A1)                                                  \
    do {                                                                      \
        _Pragma("unroll") for (int bs = 0; bs < 2; ++bs) {                    \
            int tc[4];                                                        \
            _Pragma("unroll") for (int p = 0; p < 4; ++p)                     \
                tc[p] = (buf[2 * p + 1][bs] << 16) | buf[2 * p][bs];          \
            _Pragma("unroll") for (int o = 0; o < 2; ++o) {                   \
                const int s = 2 * bs + o;                                     \
                const int msk = o ? 0x00F000F0 : 0x000F000F;                  \
                int4 bi;                                                      \
                _Pragma("unroll") for (int p = 0; p < 4; ++p) {               \
                    int vqi = (tc[p] & msk) | 0x64006400;                     \
                    f16x2 vq = __builtin_bit_cast(f16x2, vqi);                \
                    f16x2 r = (vq - vz[s]) * vs[s];                           \
                    bi[p] = __builtin_bit_cast(int, r);                       \
                }                                                             \
                f16x8 b = __builtin_bit_cast(f16x8, bi);                      \
                acc0[s] = __builtin_amdgcn_mfma_f32_16x16x32_f16(A0, b, acc0[s], 0, 0, 0); \
                acc1[s] = __builtin_amdgcn_mfma_f32_16x16x32_f16(A1, b, acc1[s], 0, 0, 0); \
            }                                                                 \
        }                                                                     \
    } while (0)

    // prologue: t=0 data + group w*4 expanded + group w*4+1 raw in flight
    QLD(qa);
    GRP_LOAD(w * 4);
    GRP_EXPAND();
    GRP_LOAD(w * 4 + 1);
    ALD(afa0, afa1, 0);

#pragma unroll
    for (int tt = 0; tt < 8; ++tt) {
        QLD(qb);                        // rows for t0+1
        ALD(afb0, afb1, 2 * tt + 1);    // A frags for t0+1
        if (tt != 0 && (tt & 1) == 0) { // group boundary at t0 = 4,8,12
            GRP_EXPAND();               // expand group loaded 4 t ago
            GRP_LOAD(w * 4 + tt / 2 + 1);
        }
        COMPUTE(qa, afa0, afa1);        // t0
        if (tt < 7) {
            QLD(qa);                    // rows for t0+2
            ALD(afa0, afa1, 2 * tt + 2);
        }
        COMPUTE(qb, afb0, afb1);        // t0+1
    }

    // per-wave partial C -> LDS. C/D: row = h*4 + r, phys col = 4c + s
#pragma unroll
    for (int s = 0; s < 4; ++s)
#pragma unroll
        for (int r = 0; r < 4; ++r) {
            red[w * 2048 + (h * 4 + r) * 64 + 4 * c + s] = acc0[s][r];
            red[w * 2048 + (16 + h * 4 + r) * 64 + 4 * c + s] = acc1[s][r];
        }

    __syncthreads();

    // cross-wave reduce + bias + store
#pragma unroll
    for (int i = 0; i < 4; ++i) {
        int e = i * 512 + tid;       // 0..2047
        float sum = 0.f;
#pragma unroll
        for (int ww = 0; ww < 8; ++ww) sum += red[ww * 2048 + e];
        int m = e >> 6;
        int n = n0 + (e & 63);
        out[(size_t)m * NOUT + n] = sum + bias[n];
    }
}

extern "C" void kernel_launch(void* const* d_in, const int* in_sizes, int n_in,
                              void* d_out, int out_size, void* d_ws, size_t ws_size,
                              hipStream_t stream) {
    const float* x       = (const float*)d_in[0];
    const int*   qweight = (const int*)d_in[1];
    const float* scales  = (const float*)d_in[2];
    const int*   qzeros  = (const int*)d_in[3];
    const float* bias    = (const float*)d_in[4];

    _Float16* aws = (_Float16*)d_ws;   // 256 KB A-fragment scratch
    float* out = (float*)d_out;

    prep_a_kernel<<<64, 256, 0, stream>>>(x, aws);
    q4gemm_kernel<<<500, 512, 0, stream>>>(qweight, scales, qzeros, bias, aws, out);
}

// Round 6
// 50.471 us; speedup vs baseline: 1.0774x; 1.0774x over previous
//
#include <hip/hip_runtime.h>
#include <hip/hip_bf16.h>

// int4-dequant GEMM, M=32 (last token), K=4096, N=32000 (of 32064 padded).
// qweight [K][16032] int32, ONE BYTE per word (upper 24 bits zero):
//   lo nibble = even col, hi nibble = odd col. w[k][n] = (q - z)*s, g = k/128.
//
// Round-4 structure + coalesced prep (r5), NO nontemporal loads (r5's nt on
// qweight cost ~3.5us; r3's regression was nt + unprefetched x loads).
//  - prep packs A (x last token, f32->f16) into d_ws fragments; shared
//    k-bijection kappa(h,j)=8h+j for A and B so HW k-order cancels.
//  - aws A-fragments double-buffered (prefetched 1 k-step ahead)
//  - scales/qzeros raw words prefetched 1 group (4 t) ahead
//  - dequant: tcomb=(w1<<16)|w0, mask-only nibble extract:
//    even cols: (tcomb & 0x000F000F)|0x64006400, vz=1024+z,   vs=s
//    odd  cols: (tcomb & 0x00F000F0)|0x64006400, vz=1024+16z, vs=s/16
//    (vq - vz exact integer diff in f16; single rounding on *vs)
// Lane c owns phys cols 4c+s; one dwordx2/row covers all 4 sub-tiles.

typedef _Float16 f16x8 __attribute__((ext_vector_type(8)));
typedef _Float16 f16x2 __attribute__((ext_vector_type(2)));
typedef float f32x4 __attribute__((ext_vector_type(4)));
typedef int i32x2 __attribute__((ext_vector_type(2)));

#define K_DIM 4096
#define NP 16032       // packed words per qweight/qzeros row
#define NSC 32064      // scales row pitch
#define NOUT 32000
#define S_LEN 64
#define QROWB ((size_t)NP * 4)          // bytes per qweight row
#define QSTEP (32u * (uint32_t)NP * 4u) // byte advance per k-step (32 rows)

// ---- pre-kernel: pack x[:,63,:] (f32) into A fragments (f16) ----
// aws[((ks*2 + mblk)*64 + h*16 + (m&15))*8 + j] = A[m][32ks + 8h + j]
// Thread (m, q): reads 32 B contiguous (k = 8q..8q+7) -> fully coalesced;
// writes one 16 B fragment (scattered, fire-and-forget).
__global__ void prep_a_kernel(const float* __restrict__ x,
                              _Float16* __restrict__ aws) {
    int tid = blockIdx.x * 256 + threadIdx.x;   // 0..16383
    int m = tid >> 9;           // 0..31
    int q = tid & 511;          // 8-wide k group
    const float* xp = x + ((size_t)m * S_LEN + (S_LEN - 1)) * K_DIM + q * 8;
    f32x4 u0 = *(const f32x4*)xp;
    f32x4 u1 = *(const f32x4*)(xp + 4);
    int ks = q >> 2;
    int h = q & 3;
    int mblk = m >> 4;
    f16x8 d;
#pragma unroll
    for (int j = 0; j < 4; ++j) {
        d[j] = (_Float16)u0[j];
        d[4 + j] = (_Float16)u1[j];
    }
    *(f16x8*)(aws + ((size_t)((ks * 2 + mblk) * 64 + h * 16 + (m & 15))) * 8) = d;
}

// ---- main kernel ----
__global__ __launch_bounds__(512, 4)
void q4gemm_kernel(const int* __restrict__ qw,
                   const float* __restrict__ scales,
                   const int* __restrict__ qzeros,
                   const float* __restrict__ bias,
                   const _Float16* __restrict__ aws,
                   float* __restrict__ out) {
    __shared__ float red[8 * 2048];   // 64 KB: per-wave partial C tiles

    const int tid = threadIdx.x;
    const int w = tid >> 6;          // wave 0..7 (K-chunk: k in [512w, 512w+512))
    const int l = tid & 63;
    const int h = l >> 4;            // k lane-group 0..3 (rows 8h+j)
    const int c = l & 15;            // lane's column group: phys cols 4c+s
    const int n0 = blockIdx.x * 64;
    const int np0 = n0 >> 1;

    const char* qwb = (const char*)qw;
    uint32_t qoff = (uint32_t)((w * 512 + 8 * h) * (size_t)NP + np0 + 2 * c) * 4u;

    f32x4 acc0[4] = {};   // mblk 0, sub s = 2*bs+o
    f32x4 acc1[4] = {};   // mblk 1
    f16x2 vz[4], vs[4];   // expanded per-group constants
    f32x4 gsc;            // raw next-group scales
    i32x2 gzw;            // raw next-group zeros
    i32x2 qa[8], qb[8];
    f16x8 afa0, afa1, afb0, afb1;

#define QLD(buf)                                                              \
    do {                                                                      \
        _Pragma("unroll") for (int j = 0; j < 8; ++j)                         \
            buf[j] = *(const i32x2*)(qwb + qoff + (size_t)j * QROWB);         \
        qoff += QSTEP;                                                        \
    } while (0)

#define GRP_LOAD(g)                                                           \
    do {                                                                      \
        int gg = (g) > 31 ? 31 : (g);                                         \
        gsc = *(const f32x4*)(scales + (size_t)gg * NSC + n0 + 4 * c);        \
        gzw = *(const i32x2*)(qzeros + (size_t)gg * NP + np0 + 2 * c);        \
    } while (0)

#define GRP_EXPAND()                                                          \
    do {                                                                      \
        _Pragma("unroll") for (int s = 0; s < 4; ++s) {                       \
            const int bs = s >> 1, o = s & 1;                                 \
            int zn = (gzw[bs] >> (4 * o)) & 15;                               \
            int z16 = 0x6400 | (o ? (zn << 4) : zn);                          \
            int zp = z16 | (z16 << 16);                                       \
            vz[s] = __builtin_bit_cast(f16x2, zp);                            \
            float sf = gsc[s] * (o ? 0.0625f : 1.0f);                         \
            _Float16 hf = (_Float16)sf;                                       \
            f16x2 sp = {hf, hf};                                              \
            vs[s] = sp;                                                       \
        }                                                                     \
    } while (0)

#define ALD(A0, A1, tloc)                                                     \
    do {                                                                      \
        int ksg_ = w * 16 + (tloc);                                           \
        A0 = *(const f16x8*)(aws + ((size_t)(ksg_ * 2 + 0) * 64 + l) * 8);    \
        A1 = *(const f16x8*)(aws + ((size_t)(ksg_ * 2 + 1) * 64 + l) * 8);    \
    } while (0)

#define COMPUTE(buf, A0, A1)                                                  \
    do {                                                                      \
        _Pragma("unroll") for (int bs = 0; bs < 2; ++bs) {                    \
            int tc[4];                                                        \
            _Pragma("unroll") for (int p = 0; p < 4; ++p)                     \
                tc[p] = (buf[2 * p + 1][bs] << 16) | buf[2 * p][bs];          \
            _Pragma("unroll") for (int o = 0; o < 2; ++o) {                   \
                const int s = 2 * bs + o;                                     \
                const int msk = o ? 0x00F000F0 : 0x000F000F;                  \
                int4 bi;                                                      \
                _Pragma("unroll") for (int p = 0; p < 4; ++p) {               \
                    int vqi = (tc[p] & msk) | 0x64006400;                     \
                    f16x2 vq = __builtin_bit_cast(f16x2, vqi);                \
                    f16x2 r = (vq - vz[s]) * vs[s];                           \
                    bi[p] = __builtin_bit_cast(int, r);                       \
                }                                                             \
                f16x8 b = __builtin_bit_cast(f16x8, bi);                      \
                acc0[s] = __builtin_amdgcn_mfma_f32_16x16x32_f16(A0, b, acc0[s], 0, 0, 0); \
                acc1[s] = __builtin_amdgcn_mfma_f32_16x16x32_f16(A1, b, acc1[s], 0, 0, 0); \
            }                                                                 \
        }                                                                     \
    } while (0)

    // prologue: t=0 data + group w*4 expanded + group w*4+1 raw in flight
    QLD(qa);
    GRP_LOAD(w * 4);
    GRP_EXPAND();
    GRP_LOAD(w * 4 + 1);
    ALD(afa0, afa1, 0);

#pragma unroll
    for (int tt = 0; tt < 8; ++tt) {
        QLD(qb);                        // rows for t0+1
        ALD(afb0, afb1, 2 * tt + 1);    // A frags for t0+1
        if (tt != 0 && (tt & 1) == 0) { // group boundary at t0 = 4,8,12
            GRP_EXPAND();               // expand group loaded 4 t ago
            GRP_LOAD(w * 4 + tt / 2 + 1);
        }
        COMPUTE(qa, afa0, afa1);        // t0
        if (tt < 7) {
            QLD(qa);                    // rows for t0+2
            ALD(afa0, afa1, 2 * tt + 2);
        }
        COMPUTE(qb, afb0, afb1);        // t0+1
    }

    // per-wave partial C -> LDS. C/D: row = h*4 + r, phys col = 4c + s
#pragma unroll
    for (int s = 0; s < 4; ++s)
#pragma unroll
        for (int r = 0; r < 4; ++r) {
            red[w * 2048 + (h * 4 + r) * 64 + 4 * c + s] = acc0[s][r];
            red[w * 2048 + (16 + h * 4 + r) * 64 + 4 * c + s] = acc1[s][r];
        }

    __syncthreads();

    // cross-wave reduce + bias + store
#pragma unroll
    for (int i = 0; i < 4; ++i) {
        int e = i * 512 + tid;       // 0..2047
        float sum = 0.f;
#pragma unroll
        for (int ww = 0; ww < 8; ++ww) sum += red[ww * 2048 + e];
        int m = e >> 6;
        int n = n0 + (e & 63);
        out[(size_t)m * NOUT + n] = sum + bias[n];
    }
}

extern "C" void kernel_launch(void* const* d_in, const int* in_sizes, int n_in,
                              void* d_out, int out_size, void* d_ws, size_t ws_size,
                              hipStream_t stream) {
    const float* x       = (const float*)d_in[0];
    const int*   qweight = (const int*)d_in[1];
    const float* scales  = (const float*)d_in[2];
    const int*   qzeros  = (const int*)d_in[3];
    const float* bias    = (const float*)d_in[4];

    _Float16* aws = (_Float16*)d_ws;   // 256 KB A-fragment scratch
    float* out = (float*)d_out;

    prep_a_kernel<<<64, 256, 0, stream>>>(x, aws);
    q4gemm_kernel<<<500, 512, 0, stream>>>(qweight, scales, qzeros, bias, aws, out);
}